// Round 7
// baseline (1343.384 us; speedup 1.0000x reference)
//
#include <hip/hip_runtime.h>
#include <hip/hip_fp16.h>
#include <cstdint>
#include <cstddef>

typedef unsigned short u16t;
typedef __bf16 bf16x8 __attribute__((ext_vector_type(8)));
typedef float f32x4 __attribute__((ext_vector_type(4)));
typedef unsigned short u16x8 __attribute__((ext_vector_type(8)));
typedef unsigned short u16x4 __attribute__((ext_vector_type(4)));

#define BT_ROWS 51200   // B*T
#define MODEL 512
#define FFNH 2048

__device__ __forceinline__ float bf2f(u16t u) {
  union { unsigned int i; float f; } v; v.i = ((unsigned int)u) << 16; return v.f;
}
__device__ __forceinline__ u16t f2bf(float f) {
  union { float f; unsigned int i; } v; v.f = f;
  return (u16t)((v.i + 0x7fffu + ((v.i >> 16) & 1u)) >> 16);
}
// dt: 0 = bf16, 1 = fp32, 2 = fp16
__device__ __forceinline__ float ldf(const void* p, size_t i, int dt) {
  if (dt == 1) return ((const float*)p)[i];
  u16t u = ((const u16t*)p)[i];
  if (dt == 0) return bf2f(u);
  __half h; *(u16t*)&h = u; return __half2float(h);
}
__device__ __forceinline__ void stf(void* p, size_t i, int dt, float f) {
  if (dt == 1) { ((float*)p)[i] = f; }
  else if (dt == 0) { ((u16t*)p)[i] = f2bf(f); }
  else { __half h = __float2half(f); ((u16t*)p)[i] = *(u16t*)&h; }
}
__device__ __forceinline__ void gl2lds16(const void* g, void* l) {
  __builtin_amdgcn_global_load_lds((const __attribute__((address_space(1))) void*)g,
                                   (__attribute__((address_space(3))) void*)l, 16, 0, 0);
}

// ---------------- dtype probe on w1: ONE block, 8 prefetched loads ----------------
__global__ __launch_bounds__(256) void detect_dtype_k(const unsigned int* __restrict__ w1,
                                                      int* __restrict__ dflag) {
  __shared__ int sh[8];
  unsigned int wb[8];
#pragma unroll
  for (int it = 0; it < 8; it++) wb[it] = w1[it * 256 + threadIdx.x];  // 8 KB, in-bounds all dtypes
  int a = 0, bc = 0;
#pragma unroll
  for (int it = 0; it < 8; it++) {
    unsigned int w = wb[it];
    u16t lo = (u16t)(w & 0xffffu), hi = (u16t)(w >> 16);
    float flo = bf2f(lo);
    a += (!(fabsf(flo) < 0.25f)) ? 1 : 0;             // fires only for fp32 mantissa noise
    __half hh; *(u16t*)&hh = hi; float fhi = __half2float(hh);
    bc += (fabsf(fhi) > 0.25f && fabsf(fhi) < 256.f) ? 1 : 0;  // fires for bf16 bit patterns
  }
#pragma unroll
  for (int o = 32; o; o >>= 1) { a += __shfl_xor(a, o); bc += __shfl_xor(bc, o); }
  int w = threadIdx.x >> 6;
  if ((threadIdx.x & 63) == 0) { sh[w] = a; sh[4 + w] = bc; }
  __syncthreads();
  if (threadIdx.x == 0) {
    int A = sh[0] + sh[1] + sh[2] + sh[3];
    int B = sh[4] + sh[5] + sh[6] + sh[7];
    dflag[0] = (A > 128) ? 1 : ((B < 128) ? 2 : 0);   // 1=fp32, 2=fp16, 0=bf16
  }
}

// ---------------- Mask layout probe: flag=1 if byte-packed ----------------
__global__ __launch_bounds__(256) void detect_mask_k(const unsigned int* __restrict__ msk,
                                                     int* __restrict__ flag) {
  int i = blockIdx.x * 256 + threadIdx.x;
  int bad = 0;
  if (i < 12800) bad = (msk[i] > 1u) ? 1 : 0;        // exactly 51200 bytes, safe for int8 & int32
  unsigned long long bl = __ballot(bad);
  if ((threadIdx.x & 63) == 0 && bl) atomicOr(flag, 1);
}

// ---------------- RMSNorm: one wave per row of 512, output bf16 ----------------
__global__ __launch_bounds__(256) void rmsnorm_k(const void* __restrict__ seq,
                                                 const void* __restrict__ w,
                                                 const int* __restrict__ dfp,
                                                 u16t* __restrict__ xn) {
  const int dt = dfp[0];
  int row = blockIdx.x * 4 + (threadIdx.x >> 6);
  int lane = threadIdx.x & 63;
  size_t base = (size_t)row * MODEL + lane * 8;
  float x[8]; float ss = 0.f;
  if (dt == 0) {
    u16x8 xv = *(const u16x8*)((const u16t*)seq + base);
#pragma unroll
    for (int j = 0; j < 8; j++) { x[j] = bf2f(xv[j]); ss += x[j] * x[j]; }
  } else if (dt == 1) {
    const f32x4* p = (const f32x4*)((const float*)seq + base);
    f32x4 va = p[0], vb = p[1];
#pragma unroll
    for (int j = 0; j < 4; j++) { x[j] = va[j]; x[4 + j] = vb[j]; }
#pragma unroll
    for (int j = 0; j < 8; j++) ss += x[j] * x[j];
  } else {
#pragma unroll
    for (int j = 0; j < 8; j++) { x[j] = ldf(seq, base + j, dt); ss += x[j] * x[j]; }
  }
#pragma unroll
  for (int o = 32; o; o >>= 1) ss += __shfl_xor(ss, o);
  float rstd = rsqrtf(ss * (1.f / 512.f) + 1.1920929e-07f);
  u16x8 ov;
#pragma unroll
  for (int j = 0; j < 8; j++) ov[j] = f2bf(x[j] * rstd * ldf(w, lane * 8 + j, dt));
  *(u16x8*)(xn + base) = ov;
}

// ---------------- Transpose (R x C) -> (C x R) with dtype conversion to bf16 ----------------
__global__ __launch_bounds__(256) void transpose_k(const void* __restrict__ src,
                                                   u16t* __restrict__ dst,
                                                   const int* __restrict__ dfp,
                                                   int R, int C) {
  const int dt = dfp[0];
  __shared__ u16t tile[32][33];
  int x = threadIdx.x & 31, y = threadIdx.x >> 5;
  int c0 = blockIdx.x * 32, r0 = blockIdx.y * 32;
#pragma unroll
  for (int i = 0; i < 32; i += 8)
    tile[y + i][x] = f2bf(ldf(src, (size_t)(r0 + y + i) * C + c0 + x, dt));
  __syncthreads();
#pragma unroll
  for (int i = 0; i < 32; i += 8) dst[(size_t)(c0 + y + i) * R + r0 + x] = tile[x][y + i];
}

// ---------------- Cast w3 (2048x512) to bf16, layout unchanged ----------------
__global__ __launch_bounds__(256) void cast_w3_k(const void* __restrict__ w3,
                                                 const int* __restrict__ dfp,
                                                 u16t* __restrict__ w3bf) {
  const int dt = dfp[0];
  size_t i = (size_t)blockIdx.x * 256 + threadIdx.x;   // grid 4096 -> 1,048,576 elems
  w3bf[i] = f2bf(ldf(w3, i, dt));
}

// ---------------- qk[b][n][d] = sum_e wk[n][d][e] * q[b][n][e] ----------------
__global__ __launch_bounds__(64) void qk_k(const void* __restrict__ q,
                                           const void* __restrict__ wk,
                                           const int* __restrict__ dfp,
                                           float* __restrict__ qkg) {
  const int dt = dfp[0];
  int bn = blockIdx.x;            // b*8+n
  int n = bn & 7, d = threadIdx.x;
  float s = 0.f;
#pragma unroll 8
  for (int e = 0; e < 64; e++)
    s += ldf(wk, ((size_t)(n * 64 + d) << 6) + e, dt) * ldf(q, ((size_t)bn << 6) + e, dt);
  qkg[((size_t)bn << 6) + d] = s;
}

// ---------------- w3qk[n][b][k] = sum_d w3[k][n*64+d] * qk[b][n][d] ----------------
__global__ __launch_bounds__(256) void w3qk_k(const void* __restrict__ w3,
                                              const float* __restrict__ qkg,
                                              const int* __restrict__ dfp,
                                              float* __restrict__ w3qk) {
  const int dt = dfp[0];
  const int n = blockIdx.x;                 // 0..7
  const int k = blockIdx.y * 256 + threadIdx.x;   // 0..2047
  const int bh = blockIdx.z;                // 0..1 (b-half)
  float w3row[64];
#pragma unroll 16
  for (int d = 0; d < 64; d++) w3row[d] = ldf(w3, ((size_t)k << 9) + n * 64 + d, dt);
  for (int b = bh * 128; b < bh * 128 + 128; b++) {
    const float* qp = qkg + ((size_t)(b * 8 + n) << 6);
    float s = 0.f;
#pragma unroll 16
    for (int d = 0; d < 64; d++) s += w3row[d] * qp[d];
    w3qk[((size_t)(n * 256 + b) << 11) + k] = s;
  }
}

// LDS K-group XOR swizzle (gemm1): physical group = logical ^ (row & 7).
// ---------------- GEMM1: Act = silu(Xn@w1) * (Xn@w2), BM=128 BN=64 BK=64 ----------------
__global__ __launch_bounds__(256, 4) void ffn_gemm1(const u16t* __restrict__ Xn,
                                                    const u16t* __restrict__ W1t,
                                                    const u16t* __restrict__ W2t,
                                                    u16t* __restrict__ Act) {
  __shared__ u16t As[128 * 64];
  __shared__ u16t B1s[64 * 64];
  __shared__ u16t B2s[64 * 64];
  const int tid = threadIdx.x;
  const int lane = tid & 63;
  const int wave = tid >> 6;
  const int wr = wave >> 1, wc = wave & 1;
  const int quad = lane >> 4, l16 = lane & 15;
  const int nBase = blockIdx.x * 64;
  const int mBase = blockIdx.y * 128;
  const int wuBase = tid & ~63;

  f32x4 acc1[4][2], acc2[4][2];
  const f32x4 zf = {0.f, 0.f, 0.f, 0.f};
#pragma unroll
  for (int i = 0; i < 4; i++)
#pragma unroll
    for (int j = 0; j < 2; j++) { acc1[i][j] = zf; acc2[i][j] = zf; }

  for (int kt = 0; kt < MODEL; kt += 64) {
#pragma unroll
    for (int c = 0; c < 4; c++) {
      int chunk = c * 256 + tid;
      int r = chunk >> 3, k8 = (chunk & 7) ^ (r & 7);
      gl2lds16(Xn + (size_t)(mBase + r) * MODEL + kt + k8 * 8, As + (size_t)(c * 256 + wuBase) * 8);
    }
#pragma unroll
    for (int c = 0; c < 2; c++) {
      int chunk = c * 256 + tid;
      int r = chunk >> 3, k8 = (chunk & 7) ^ (r & 7);
      gl2lds16(W1t + (size_t)(nBase + r) * MODEL + kt + k8 * 8, B1s + (size_t)(c * 256 + wuBase) * 8);
      gl2lds16(W2t + (size_t)(nBase + r) * MODEL + kt + k8 * 8, B2s + (size_t)(c * 256 + wuBase) * 8);
    }
    __syncthreads();
#pragma unroll
    for (int ks = 0; ks < 64; ks += 32) {
      bf16x8 a[4], b1[2], b2[2];
      const int sw = (ks >> 3) + quad;
#pragma unroll
      for (int mi = 0; mi < 4; mi++) {
        int row = wr * 64 + mi * 16 + l16;
        a[mi] = *(const bf16x8*)(As + row * 64 + ((sw ^ (row & 7)) << 3));
      }
#pragma unroll
      for (int ni = 0; ni < 2; ni++) {
        int row = wc * 32 + ni * 16 + l16;
        b1[ni] = *(const bf16x8*)(B1s + row * 64 + ((sw ^ (row & 7)) << 3));
        b2[ni] = *(const bf16x8*)(B2s + row * 64 + ((sw ^ (row & 7)) << 3));
      }
#pragma unroll
      for (int mi = 0; mi < 4; mi++)
#pragma unroll
        for (int ni = 0; ni < 2; ni++) {
          acc1[mi][ni] = __builtin_amdgcn_mfma_f32_16x16x32_bf16(a[mi], b1[ni], acc1[mi][ni], 0, 0, 0);
          acc2[mi][ni] = __builtin_amdgcn_mfma_f32_16x16x32_bf16(a[mi], b2[ni], acc2[mi][ni], 0, 0, 0);
        }
    }
    __syncthreads();
  }
#pragma unroll
  for (int mi = 0; mi < 4; mi++)
#pragma unroll
    for (int ni = 0; ni < 2; ni++)
#pragma unroll
      for (int r = 0; r < 4; r++) {
        int row = mBase + wr * 64 + mi * 16 + quad * 4 + r;
        int col = nBase + wc * 32 + ni * 16 + l16;
        float g1 = acc1[mi][ni][r], g2 = acc2[mi][ni][r];
        float sl = g1 / (1.f + __expf(-g1));
        Act[(size_t)row * FFNH + col] = f2bf(sl * g2);
      }
}

// ---------------- scores: block per (chunk-batch, t-half); w3qk[b] in LDS ----------------
__global__ __launch_bounds__(512) void scores_k(const u16t* __restrict__ ActB,
                                                const void* __restrict__ seq,
                                                const float* __restrict__ qkg,
                                                const float* __restrict__ w3qk,
                                                const int* __restrict__ mask,
                                                const int* __restrict__ mflagp,
                                                const int* __restrict__ dfp,
                                                float* __restrict__ sc, int b0) {
  const int dt = dfp[0], mflag = mflagp[0];
  const int bl = blockIdx.x, bg = b0 + bl;
  const int th = blockIdx.y;
  const int tid = threadIdx.x, wave = tid >> 6, lane = tid & 63;
  __shared__ float wq[8][2048];   // 64 KB
#pragma unroll
  for (int n = 0; n < 8; n++)
#pragma unroll
    for (int i = 0; i < 4; i++)
      wq[n][i * 512 + tid] = w3qk[((size_t)(n * 256 + bg) << 11) + i * 512 + tid];
  __syncthreads();
  const int ns = lane >> 3;
  const float* qp = qkg + ((size_t)(bg * 8 + ns) << 6) + (lane & 7) * 8;
  for (int ti = wave; ti < 100; ti += 8) {
    int t = th * 100 + ti;
    const u16t* ar = ActB + ((size_t)(bl * 200 + t) << 11);
    float acc[8] = {0.f, 0.f, 0.f, 0.f, 0.f, 0.f, 0.f, 0.f};
#pragma unroll
    for (int i = 0; i < 8; i++) {
      int k = i * 256 + lane * 4;
      u16x4 a4 = *(const u16x4*)(ar + k);
      float a0 = bf2f(a4[0]), a1 = bf2f(a4[1]), a2 = bf2f(a4[2]), a3 = bf2f(a4[3]);
#pragma unroll
      for (int n = 0; n < 8; n++) {
        f32x4 wv4 = *(const f32x4*)&wq[n][k];
        acc[n] += a0 * wv4[0] + a1 * wv4[1] + a2 * wv4[2] + a3 * wv4[3];
      }
    }
    // seq residual term: lane covers seq cols lane*8..+7 -> head ns
    float sq = 0.f;
    size_t sb = ((size_t)(bg * 200 + t) << 9) + lane * 8;
    if (dt == 1) {
      const float* sp = (const float*)seq + sb;
      f32x4 s0 = *(const f32x4*)sp, s1 = *(const f32x4*)(sp + 4);
      sq = s0[0] * qp[0] + s0[1] * qp[1] + s0[2] * qp[2] + s0[3] * qp[3]
         + s1[0] * qp[4] + s1[1] * qp[5] + s1[2] * qp[6] + s1[3] * qp[7];
    } else {
#pragma unroll
      for (int j = 0; j < 8; j++) sq += ldf(seq, sb + j, dt) * qp[j];
    }
    sq += __shfl_xor(sq, 1); sq += __shfl_xor(sq, 2); sq += __shfl_xor(sq, 4);
#pragma unroll
    for (int n = 0; n < 8; n++)
#pragma unroll
      for (int o = 32; o; o >>= 1) acc[n] += __shfl_xor(acc[n], o);
    if ((lane & 7) == 0) {
      float sco = (acc[ns] + sq) * 0.125f;
      int mv = mflag ? (int)((const unsigned char*)mask)[bg * 200 + t] : mask[bg * 200 + t];
      sc[(size_t)(bg * 8 + ns) * 200 + t] = mv ? sco : -INFINITY;
    }
  }
}

// ---------------- ctx: softmax + ctxAct + w3 proj + wv proj + residuals ----------------
__global__ __launch_bounds__(512) void ctx_k(const u16t* __restrict__ ActB,
                                             const void* __restrict__ seq,
                                             const void* __restrict__ q,
                                             const void* __restrict__ wv,
                                             const u16t* __restrict__ w3bf,
                                             const float* __restrict__ sc,
                                             const int* __restrict__ dfp,
                                             int b0, void* __restrict__ out) {
  const int dt = dfp[0];
  const int bl = blockIdx.x, bg = b0 + bl;
  const int tid = threadIdx.x, wave = tid >> 6, lane = tid & 63;
  __shared__ float p_lds[8][200];
  __shared__ float ctxa[8][2048];   // 64 KB
  __shared__ float ch[512];

  { // softmax: wave = head
    int n = wave;
    float v[4];
#pragma unroll
    for (int r = 0; r < 4; r++) {
      int t = r * 64 + lane;
      v[r] = (t < 200) ? sc[(size_t)(bg * 8 + n) * 200 + t] : -INFINITY;
    }
    float mx = fmaxf(fmaxf(v[0], v[1]), fmaxf(v[2], v[3]));
#pragma unroll
    for (int o = 32; o; o >>= 1) mx = fmaxf(mx, __shfl_xor(mx, o));
    float s = 0.f, e[4];
#pragma unroll
    for (int r = 0; r < 4; r++) {
      int t = r * 64 + lane;
      if (mx == -INFINITY) e[r] = (t == 0) ? 1.f : 0.f;   // NaN guard
      else e[r] = (t < 200) ? __expf(v[r] - mx) : 0.f;
      s += e[r];
    }
#pragma unroll
    for (int o = 32; o; o >>= 1) s += __shfl_xor(s, o);
    float inv = 1.f / s;
#pragma unroll
    for (int r = 0; r < 4; r++) { int t = r * 64 + lane; if (t < 200) p_lds[n][t] = e[r] * inv; }
  }
  __syncthreads();

  float acc[8][4] = {};
  float accs = 0.f;                 // ctxSeq for (n,d) = (wave,lane) = seq col tid
  for (int t = 0; t < 200; t++) {
    u16x4 a4 = *(const u16x4*)(ActB + ((size_t)(bl * 200 + t) << 11) + tid * 4);
    float a0 = bf2f(a4[0]), a1 = bf2f(a4[1]), a2 = bf2f(a4[2]), a3 = bf2f(a4[3]);
#pragma unroll
    for (int n = 0; n < 8; n++) {
      float pv = p_lds[n][t];
      acc[n][0] += pv * a0; acc[n][1] += pv * a1; acc[n][2] += pv * a2; acc[n][3] += pv * a3;
    }
    float svv = ldf(seq, ((size_t)(bg * 200 + t) << 9) + tid, dt);
    accs += p_lds[wave][t] * svv;
  }
#pragma unroll
  for (int n = 0; n < 8; n++) {
    f32x4 v4 = {acc[n][0], acc[n][1], acc[n][2], acc[n][3]};
    *(f32x4*)&ctxa[n][tid * 4] = v4;
  }
  __syncthreads();

  // CH[n][d] = sum_k ctxa[n][k] * w3[k][n*64+d] + ctxSeq
  float chv = accs;
  {
    const u16t* wr = w3bf + wave * 64 + lane;
    for (int k4 = 0; k4 < 512; k4++) {
      f32x4 c4 = *(const f32x4*)&ctxa[wave][k4 * 4];
      chv += c4[0] * bf2f(wr[(size_t)(k4 * 4 + 0) * 512])
           + c4[1] * bf2f(wr[(size_t)(k4 * 4 + 1) * 512])
           + c4[2] * bf2f(wr[(size_t)(k4 * 4 + 2) * 512])
           + c4[3] * bf2f(wr[(size_t)(k4 * 4 + 3) * 512]);
    }
  }
  ch[tid] = chv;
  __syncthreads();

  // out[b,n,e] = sum_d CH[n][d] * wv[n][d][e] + q
  float o = 0.f;
#pragma unroll 8
  for (int d = 0; d < 64; d++)
    o += ch[wave * 64 + d] * ldf(wv, ((size_t)(wave * 64 + d) << 6) + lane, dt);
  size_t oi = (size_t)(bg * 8 + wave) * 64 + lane;
  stf(out, oi, dt, o + ldf(q, oi, dt));
}

extern "C" void kernel_launch(void* const* d_in, const int* in_sizes, int n_in,
                              void* d_out, int out_size, void* d_ws, size_t ws_size,
                              hipStream_t stream) {
  (void)in_sizes; (void)n_in; (void)out_size;
  const void* q   = d_in[0];
  const void* seq = d_in[1];
  const void* rw  = d_in[2];
  const void* w1  = d_in[3];
  const void* w2  = d_in[4];
  const void* w3  = d_in[5];
  const void* wk  = d_in[6];
  const void* wv  = d_in[7];
  const int*  msk = (const int*)d_in[8];

  char* ws = (char*)d_ws;
  size_t off = 0;
  auto alloc = [&](size_t b) { void* p = ws + off; off = (off + b + 255) & ~(size_t)255; return p; };
  int*   flags = (int*)alloc(512);            // [0]=mflag, [4]=dflag
  int*   mflag = flags + 0;
  int*   dflag = flags + 4;
  u16t*  Xn    = (u16t*)alloc((size_t)BT_ROWS * MODEL * 2);
  u16t*  W1t   = (u16t*)alloc((size_t)FFNH * MODEL * 2);
  u16t*  W2t   = (u16t*)alloc((size_t)FFNH * MODEL * 2);
  u16t*  W3bf  = (u16t*)alloc((size_t)FFNH * MODEL * 2);
  float* qkg   = (float*)alloc((size_t)256 * 8 * 64 * 4);
  float* w3qk  = (float*)alloc((size_t)8 * 256 * FFNH * 4);
  float* scb   = (float*)alloc((size_t)256 * 8 * 200 * 4);
  size_t actBytes = (ws_size > off) ? (ws_size - off) : 0;
  size_t unitB = (size_t)25 * 128 * FFNH * 2;       // 25 tiles = 16 batches = 13.1 MB
  long units = (long)(actBytes / unitB);
  if (units < 1) units = 1;
  if (units > 8) units = 8;
  int tpc = (int)units * 25;
  u16t* ActB = (u16t*)(ws + off);

  hipMemsetAsync(flags, 0, 512, stream);
  detect_dtype_k<<<dim3(1), dim3(256), 0, stream>>>((const unsigned int*)w1, dflag);
  detect_mask_k<<<dim3(50), dim3(256), 0, stream>>>((const unsigned int*)msk, mflag);

  rmsnorm_k<<<dim3(BT_ROWS / 4), dim3(256), 0, stream>>>(seq, rw, dflag, Xn);
  transpose_k<<<dim3(FFNH / 32, MODEL / 32), dim3(256), 0, stream>>>(w1, W1t, dflag, MODEL, FFNH);
  transpose_k<<<dim3(FFNH / 32, MODEL / 32), dim3(256), 0, stream>>>(w2, W2t, dflag, MODEL, FFNH);
  cast_w3_k<<<dim3(4096), dim3(256), 0, stream>>>(w3, dflag, W3bf);
  qk_k<<<dim3(2048), dim3(64), 0, stream>>>(q, wk, dflag, qkg);
  w3qk_k<<<dim3(8, 8, 2), dim3(256), 0, stream>>>(w3, qkg, dflag, w3qk);

  for (int t0 = 0; t0 < 400; t0 += tpc) {
    int tiles = (400 - t0 < tpc) ? (400 - t0) : tpc;
    int rows0 = t0 * 128;
    int b0 = rows0 / 200;            // tiles multiple of 25 -> whole batches per chunk
    int bc = tiles * 128 / 200;
    ffn_gemm1<<<dim3(FFNH / 64, tiles), dim3(256), 0, stream>>>(
        Xn + (size_t)rows0 * MODEL, W1t, W2t, ActB);
    scores_k<<<dim3(bc, 2), dim3(512), 0, stream>>>(ActB, seq, qkg, w3qk, msk, mflag, dflag, scb, b0);
    ctx_k<<<dim3(bc), dim3(512), 0, stream>>>(ActB, seq, q, wv, W3bf, scb, dflag, b0, d_out);
  }
}

// Round 8
// 1097.774 us; speedup vs baseline: 1.2237x; 1.2237x over previous
//
#include <hip/hip_runtime.h>
#include <hip/hip_fp16.h>
#include <cstdint>
#include <cstddef>

typedef unsigned short u16t;
typedef __bf16 bf16x8 __attribute__((ext_vector_type(8)));
typedef float f32x4 __attribute__((ext_vector_type(4)));
typedef unsigned short u16x8 __attribute__((ext_vector_type(8)));
typedef unsigned short u16x4 __attribute__((ext_vector_type(4)));

#define BT_ROWS 51200   // B*T
#define MODEL 512
#define FFNH 2048

__device__ __forceinline__ float bf2f(u16t u) {
  union { unsigned int i; float f; } v; v.i = ((unsigned int)u) << 16; return v.f;
}
__device__ __forceinline__ u16t f2bf(float f) {
  union { float f; unsigned int i; } v; v.f = f;
  return (u16t)((v.i + 0x7fffu + ((v.i >> 16) & 1u)) >> 16);
}
// dt: 0 = bf16, 1 = fp32, 2 = fp16
__device__ __forceinline__ float ldf(const void* p, size_t i, int dt) {
  if (dt == 1) return ((const float*)p)[i];
  u16t u = ((const u16t*)p)[i];
  if (dt == 0) return bf2f(u);
  __half h; *(u16t*)&h = u; return __half2float(h);
}
__device__ __forceinline__ void stf(void* p, size_t i, int dt, float f) {
  if (dt == 1) { ((float*)p)[i] = f; }
  else if (dt == 0) { ((u16t*)p)[i] = f2bf(f); }
  else { __half h = __float2half(f); ((u16t*)p)[i] = *(u16t*)&h; }
}
__device__ __forceinline__ void gl2lds16(const void* g, void* l) {
  __builtin_amdgcn_global_load_lds((const __attribute__((address_space(1))) void*)g,
                                   (__attribute__((address_space(3))) void*)l, 16, 0, 0);
}

// ---------------- dtype probe on w1: ONE block ----------------
__global__ __launch_bounds__(256) void detect_dtype_k(const unsigned int* __restrict__ w1,
                                                      int* __restrict__ dflag) {
  __shared__ int sh[8];
  unsigned int wb[8];
#pragma unroll
  for (int it = 0; it < 8; it++) wb[it] = w1[it * 256 + threadIdx.x];  // 8 KB, in-bounds all dtypes
  int a = 0, bc = 0;
#pragma unroll
  for (int it = 0; it < 8; it++) {
    unsigned int w = wb[it];
    u16t lo = (u16t)(w & 0xffffu), hi = (u16t)(w >> 16);
    float flo = bf2f(lo);
    a += (!(fabsf(flo) < 0.25f)) ? 1 : 0;             // fires only for fp32 mantissa noise
    __half hh; *(u16t*)&hh = hi; float fhi = __half2float(hh);
    bc += (fabsf(fhi) > 0.25f && fabsf(fhi) < 256.f) ? 1 : 0;  // fires for bf16 bit patterns
  }
#pragma unroll
  for (int o = 32; o; o >>= 1) { a += __shfl_xor(a, o); bc += __shfl_xor(bc, o); }
  int w = threadIdx.x >> 6;
  if ((threadIdx.x & 63) == 0) { sh[w] = a; sh[4 + w] = bc; }
  __syncthreads();
  if (threadIdx.x == 0) {
    int A = sh[0] + sh[1] + sh[2] + sh[3];
    int B = sh[4] + sh[5] + sh[6] + sh[7];
    dflag[0] = (A > 128) ? 1 : ((B < 128) ? 2 : 0);   // 1=fp32, 2=fp16, 0=bf16
  }
}

// ---------------- Mask layout probe: flag=1 if byte-packed ----------------
__global__ __launch_bounds__(256) void detect_mask_k(const unsigned int* __restrict__ msk,
                                                     int* __restrict__ flag) {
  int i = blockIdx.x * 256 + threadIdx.x;
  int bad = 0;
  if (i < 12800) bad = (msk[i] > 1u) ? 1 : 0;        // exactly 51200 bytes, safe for int8 & int32
  unsigned long long bl = __ballot(bad);
  if ((threadIdx.x & 63) == 0 && bl) atomicOr(flag, 1);
}

// ---------------- RMSNorm: one wave per row of 512, output bf16 ----------------
__global__ __launch_bounds__(256) void rmsnorm_k(const void* __restrict__ seq,
                                                 const void* __restrict__ w,
                                                 const int* __restrict__ dfp,
                                                 u16t* __restrict__ xn) {
  const int dt = dfp[0];
  int row = blockIdx.x * 4 + (threadIdx.x >> 6);
  int lane = threadIdx.x & 63;
  size_t base = (size_t)row * MODEL + lane * 8;
  float x[8]; float ss = 0.f;
  if (dt == 0) {
    u16x8 xv = *(const u16x8*)((const u16t*)seq + base);
#pragma unroll
    for (int j = 0; j < 8; j++) { x[j] = bf2f(xv[j]); ss += x[j] * x[j]; }
  } else if (dt == 1) {
    const f32x4* p = (const f32x4*)((const float*)seq + base);
    f32x4 va = p[0], vb = p[1];
#pragma unroll
    for (int j = 0; j < 4; j++) { x[j] = va[j]; x[4 + j] = vb[j]; }
#pragma unroll
    for (int j = 0; j < 8; j++) ss += x[j] * x[j];
  } else {
#pragma unroll
    for (int j = 0; j < 8; j++) { x[j] = ldf(seq, base + j, dt); ss += x[j] * x[j]; }
  }
#pragma unroll
  for (int o = 32; o; o >>= 1) ss += __shfl_xor(ss, o);
  float rstd = rsqrtf(ss * (1.f / 512.f) + 1.1920929e-07f);
  u16x8 ov;
#pragma unroll
  for (int j = 0; j < 8; j++) ov[j] = f2bf(x[j] * rstd * ldf(w, lane * 8 + j, dt));
  *(u16x8*)(xn + base) = ov;
}

// ---------------- Transpose (R x C) -> (C x R) with dtype conversion to bf16 ----------------
__global__ __launch_bounds__(256) void transpose_k(const void* __restrict__ src,
                                                   u16t* __restrict__ dst,
                                                   const int* __restrict__ dfp,
                                                   int R, int C) {
  const int dt = dfp[0];
  __shared__ u16t tile[32][33];
  int x = threadIdx.x & 31, y = threadIdx.x >> 5;
  int c0 = blockIdx.x * 32, r0 = blockIdx.y * 32;
#pragma unroll
  for (int i = 0; i < 32; i += 8)
    tile[y + i][x] = f2bf(ldf(src, (size_t)(r0 + y + i) * C + c0 + x, dt));
  __syncthreads();
#pragma unroll
  for (int i = 0; i < 32; i += 8) dst[(size_t)(c0 + y + i) * R + r0 + x] = tile[x][y + i];
}

// ---------------- Cast w3 (2048x512) to bf16, layout unchanged ----------------
__global__ __launch_bounds__(256) void cast_w3_k(const void* __restrict__ w3,
                                                 const int* __restrict__ dfp,
                                                 u16t* __restrict__ w3bf) {
  const int dt = dfp[0];
  size_t i = (size_t)blockIdx.x * 256 + threadIdx.x;   // grid 4096 -> 1,048,576 elems
  w3bf[i] = f2bf(ldf(w3, i, dt));
}

// ---------------- qk[b][n][d] = sum_e wk[n][d][e] * q[b][n][e] ----------------
__global__ __launch_bounds__(64) void qk_k(const void* __restrict__ q,
                                           const void* __restrict__ wk,
                                           const int* __restrict__ dfp,
                                           float* __restrict__ qkg) {
  const int dt = dfp[0];
  int bn = blockIdx.x;            // b*8+n
  int n = bn & 7, d = threadIdx.x;
  float s = 0.f;
#pragma unroll 8
  for (int e = 0; e < 64; e++)
    s += ldf(wk, ((size_t)(n * 64 + d) << 6) + e, dt) * ldf(q, ((size_t)bn << 6) + e, dt);
  qkg[((size_t)bn << 6) + d] = s;
}

// ---------------- w3qk[n][b][k] = sum_d w3[k][n*64+d] * qk[b][n][d] ----------------
// grid (8 n, 16 b-tiles); qk tile in LDS (broadcast reads); FLOP-bound.
__global__ __launch_bounds__(256) void w3qk_k(const void* __restrict__ w3,
                                              const float* __restrict__ qkg,
                                              const int* __restrict__ dfp,
                                              float* __restrict__ w3qk) {
  const int dt = dfp[0];
  const int n = blockIdx.x, bt = blockIdx.y;
  const int tid = threadIdx.x;
  __shared__ float qkl[16][64];    // 4 KB
  for (int i = tid; i < 1024; i += 256) {
    int b = i >> 6, d = i & 63;
    qkl[b][d] = qkg[((size_t)((bt * 16 + b) * 8 + n) << 6) + d];
  }
  __syncthreads();
  for (int kk = 0; kk < 8; kk++) {
    int k = kk * 256 + tid;
    float row[64];
    if (dt == 1) {
      const f32x4* wp = (const f32x4*)((const float*)w3 + ((size_t)k << 9) + n * 64);
#pragma unroll
      for (int j = 0; j < 16; j++) {
        f32x4 v = wp[j];
        row[j * 4] = v[0]; row[j * 4 + 1] = v[1]; row[j * 4 + 2] = v[2]; row[j * 4 + 3] = v[3];
      }
    } else {
#pragma unroll
      for (int d = 0; d < 64; d++) row[d] = ldf(w3, ((size_t)k << 9) + n * 64 + d, dt);
    }
#pragma unroll 4
    for (int b = 0; b < 16; b++) {
      float s = 0.f;
#pragma unroll
      for (int d = 0; d < 64; d++) s += row[d] * qkl[b][d];
      w3qk[((size_t)(n * 256 + bt * 16 + b) << 11) + k] = s;
    }
  }
}

// LDS K-group XOR swizzle (gemm1): physical group = logical ^ (row & 7).
// ---------------- GEMM1: Act = silu(Xn@w1) * (Xn@w2), BM=128 BN=64 BK=64 ----------------
__global__ __launch_bounds__(256, 4) void ffn_gemm1(const u16t* __restrict__ Xn,
                                                    const u16t* __restrict__ W1t,
                                                    const u16t* __restrict__ W2t,
                                                    u16t* __restrict__ Act) {
  __shared__ u16t As[128 * 64];
  __shared__ u16t B1s[64 * 64];
  __shared__ u16t B2s[64 * 64];
  const int tid = threadIdx.x;
  const int lane = tid & 63;
  const int wave = tid >> 6;
  const int wr = wave >> 1, wc = wave & 1;
  const int quad = lane >> 4, l16 = lane & 15;
  const int nBase = blockIdx.x * 64;
  const int mBase = blockIdx.y * 128;
  const int wuBase = tid & ~63;

  f32x4 acc1[4][2], acc2[4][2];
  const f32x4 zf = {0.f, 0.f, 0.f, 0.f};
#pragma unroll
  for (int i = 0; i < 4; i++)
#pragma unroll
    for (int j = 0; j < 2; j++) { acc1[i][j] = zf; acc2[i][j] = zf; }

  for (int kt = 0; kt < MODEL; kt += 64) {
#pragma unroll
    for (int c = 0; c < 4; c++) {
      int chunk = c * 256 + tid;
      int r = chunk >> 3, k8 = (chunk & 7) ^ (r & 7);
      gl2lds16(Xn + (size_t)(mBase + r) * MODEL + kt + k8 * 8, As + (size_t)(c * 256 + wuBase) * 8);
    }
#pragma unroll
    for (int c = 0; c < 2; c++) {
      int chunk = c * 256 + tid;
      int r = chunk >> 3, k8 = (chunk & 7) ^ (r & 7);
      gl2lds16(W1t + (size_t)(nBase + r) * MODEL + kt + k8 * 8, B1s + (size_t)(c * 256 + wuBase) * 8);
      gl2lds16(W2t + (size_t)(nBase + r) * MODEL + kt + k8 * 8, B2s + (size_t)(c * 256 + wuBase) * 8);
    }
    __syncthreads();
#pragma unroll
    for (int ks = 0; ks < 64; ks += 32) {
      bf16x8 a[4], b1[2], b2[2];
      const int sw = (ks >> 3) + quad;
#pragma unroll
      for (int mi = 0; mi < 4; mi++) {
        int row = wr * 64 + mi * 16 + l16;
        a[mi] = *(const bf16x8*)(As + row * 64 + ((sw ^ (row & 7)) << 3));
      }
#pragma unroll
      for (int ni = 0; ni < 2; ni++) {
        int row = wc * 32 + ni * 16 + l16;
        b1[ni] = *(const bf16x8*)(B1s + row * 64 + ((sw ^ (row & 7)) << 3));
        b2[ni] = *(const bf16x8*)(B2s + row * 64 + ((sw ^ (row & 7)) << 3));
      }
#pragma unroll
      for (int mi = 0; mi < 4; mi++)
#pragma unroll
        for (int ni = 0; ni < 2; ni++) {
          acc1[mi][ni] = __builtin_amdgcn_mfma_f32_16x16x32_bf16(a[mi], b1[ni], acc1[mi][ni], 0, 0, 0);
          acc2[mi][ni] = __builtin_amdgcn_mfma_f32_16x16x32_bf16(a[mi], b2[ni], acc2[mi][ni], 0, 0, 0);
        }
    }
    __syncthreads();
  }
#pragma unroll
  for (int mi = 0; mi < 4; mi++)
#pragma unroll
    for (int ni = 0; ni < 2; ni++)
#pragma unroll
      for (int r = 0; r < 4; r++) {
        int row = mBase + wr * 64 + mi * 16 + quad * 4 + r;
        int col = nBase + wc * 32 + ni * 16 + l16;
        float g1 = acc1[mi][ni][r], g2 = acc2[mi][ni][r];
        float sl = g1 / (1.f + __expf(-g1));
        Act[(size_t)row * FFNH + col] = f2bf(sl * g2);
      }
}

// ---------------- scores: block per (chunk-batch, t-half); w3qk[b] in LDS ----------------
__global__ __launch_bounds__(512) void scores_k(const u16t* __restrict__ ActB,
                                                const void* __restrict__ seq,
                                                const float* __restrict__ qkg,
                                                const float* __restrict__ w3qk,
                                                const int* __restrict__ mask,
                                                const int* __restrict__ mflagp,
                                                const int* __restrict__ dfp,
                                                float* __restrict__ sc, int b0) {
  const int dt = dfp[0], mflag = mflagp[0];
  const int bl = blockIdx.x, bg = b0 + bl;
  const int th = blockIdx.y;
  const int tid = threadIdx.x, wave = tid >> 6, lane = tid & 63;
  __shared__ float wq[8][2048];   // 64 KB
#pragma unroll
  for (int n = 0; n < 8; n++)
#pragma unroll
    for (int i = 0; i < 4; i++)
      wq[n][i * 512 + tid] = w3qk[((size_t)(n * 256 + bg) << 11) + i * 512 + tid];
  __syncthreads();
  const int ns = lane >> 3;
  const float* qp = qkg + ((size_t)(bg * 8 + ns) << 6) + (lane & 7) * 8;
  for (int ti = wave; ti < 100; ti += 8) {
    int t = th * 100 + ti;
    const u16t* ar = ActB + ((size_t)(bl * 200 + t) << 11);
    float acc[8] = {0.f, 0.f, 0.f, 0.f, 0.f, 0.f, 0.f, 0.f};
#pragma unroll
    for (int i = 0; i < 8; i++) {
      int k = i * 256 + lane * 4;
      u16x4 a4 = *(const u16x4*)(ar + k);
      float a0 = bf2f(a4[0]), a1 = bf2f(a4[1]), a2 = bf2f(a4[2]), a3 = bf2f(a4[3]);
#pragma unroll
      for (int n = 0; n < 8; n++) {
        f32x4 wv4 = *(const f32x4*)&wq[n][k];
        acc[n] += a0 * wv4[0] + a1 * wv4[1] + a2 * wv4[2] + a3 * wv4[3];
      }
    }
    float sq = 0.f;
    size_t sb = ((size_t)(bg * 200 + t) << 9) + lane * 8;
    if (dt == 1) {
      const float* sp = (const float*)seq + sb;
      f32x4 s0 = *(const f32x4*)sp, s1 = *(const f32x4*)(sp + 4);
      sq = s0[0] * qp[0] + s0[1] * qp[1] + s0[2] * qp[2] + s0[3] * qp[3]
         + s1[0] * qp[4] + s1[1] * qp[5] + s1[2] * qp[6] + s1[3] * qp[7];
    } else {
#pragma unroll
      for (int j = 0; j < 8; j++) sq += ldf(seq, sb + j, dt) * qp[j];
    }
    sq += __shfl_xor(sq, 1); sq += __shfl_xor(sq, 2); sq += __shfl_xor(sq, 4);
#pragma unroll
    for (int n = 0; n < 8; n++)
#pragma unroll
      for (int o = 32; o; o >>= 1) acc[n] += __shfl_xor(acc[n], o);
    if ((lane & 7) == 0) {
      float sco = (acc[ns] + sq) * 0.125f;
      int mv = mflag ? (int)((const unsigned char*)mask)[bg * 200 + t] : mask[bg * 200 + t];
      sc[(size_t)(bg * 8 + ns) * 200 + t] = mv ? sco : -INFINITY;
    }
  }
}

// ---------------- pctx: block (bl, t-half); register-only partial ctxA + ctxSeq ----------------
__global__ __launch_bounds__(512) void pctx_k(const u16t* __restrict__ ActB,
                                              const void* __restrict__ seq,
                                              const float* __restrict__ sc,
                                              const int* __restrict__ dfp,
                                              int b0, float* __restrict__ ctxaG,
                                              float* __restrict__ ctxsG) {
  const int dt = dfp[0];
  const int bl = blockIdx.x, bg = b0 + bl, th = blockIdx.y;
  const int tid = threadIdx.x, wave = tid >> 6, lane = tid & 63;
  __shared__ float p_lds[8][200];

  { // softmax (full T, redundant across th — cheap)
    int n = wave;
    float v[4];
#pragma unroll
    for (int r = 0; r < 4; r++) {
      int t = r * 64 + lane;
      v[r] = (t < 200) ? sc[(size_t)(bg * 8 + n) * 200 + t] : -INFINITY;
    }
    float mx = fmaxf(fmaxf(v[0], v[1]), fmaxf(v[2], v[3]));
#pragma unroll
    for (int o = 32; o; o >>= 1) mx = fmaxf(mx, __shfl_xor(mx, o));
    float s = 0.f, e[4];
#pragma unroll
    for (int r = 0; r < 4; r++) {
      int t = r * 64 + lane;
      if (mx == -INFINITY) e[r] = (t == 0) ? 1.f : 0.f;   // NaN guard
      else e[r] = (t < 200) ? __expf(v[r] - mx) : 0.f;
      s += e[r];
    }
#pragma unroll
    for (int o = 32; o; o >>= 1) s += __shfl_xor(s, o);
    float inv = 1.f / s;
#pragma unroll
    for (int r = 0; r < 4; r++) { int t = r * 64 + lane; if (t < 200) p_lds[n][t] = e[r] * inv; }
  }
  __syncthreads();

  float acc[8][4] = {};
  float accs = 0.f;
#pragma unroll 4
  for (int ti = 0; ti < 100; ti++) {
    int t = th * 100 + ti;
    u16x4 a4 = *(const u16x4*)(ActB + ((size_t)(bl * 200 + t) << 11) + tid * 4);
    float svv = ldf(seq, ((size_t)(bg * 200 + t) << 9) + tid, dt);
    float a0 = bf2f(a4[0]), a1 = bf2f(a4[1]), a2 = bf2f(a4[2]), a3 = bf2f(a4[3]);
#pragma unroll
    for (int n = 0; n < 8; n++) {
      float pv = p_lds[n][t];
      acc[n][0] += pv * a0; acc[n][1] += pv * a1; acc[n][2] += pv * a2; acc[n][3] += pv * a3;
    }
    accs += p_lds[wave][t] * svv;
  }
#pragma unroll
  for (int n = 0; n < 8; n++) {
    f32x4 v4 = {acc[n][0], acc[n][1], acc[n][2], acc[n][3]};
    *(f32x4*)&ctxaG[(((size_t)(th * 128 + bl) * 8 + n) << 11) + tid * 4] = v4;
  }
  ctxsG[(size_t)(th * 128 + bl) * 512 + tid] = accs;
}

// ---------------- chout: sum halves, w3 proj, wv proj, residual ----------------
__global__ __launch_bounds__(512) void chout_k(const float* __restrict__ ctxaG,
                                               const float* __restrict__ ctxsG,
                                               const u16t* __restrict__ w3bf,
                                               const void* __restrict__ wv,
                                               const void* __restrict__ q,
                                               const int* __restrict__ dfp,
                                               int b0, void* __restrict__ out) {
  const int dt = dfp[0];
  const int bl = blockIdx.x, bg = b0 + bl;
  const int tid = threadIdx.x, wave = tid >> 6, lane = tid & 63;
  __shared__ float ctxa[8][2048];   // 64 KB
  __shared__ float ch[512];
#pragma unroll
  for (int i = 0; i < 32; i++) {
    int idx = i * 512 + tid;
    ctxa[idx >> 11][idx & 2047] =
        ctxaG[(((size_t)bl * 8) << 11) + idx] + ctxaG[(((size_t)(128 + bl) * 8) << 11) + idx];
  }
  __syncthreads();

  float chv = ctxsG[(size_t)bl * 512 + tid] + ctxsG[(size_t)(128 + bl) * 512 + tid];
  {
    const u16t* wr = w3bf + wave * 64 + lane;
    for (int k4 = 0; k4 < 512; k4++) {
      f32x4 c4 = *(const f32x4*)&ctxa[wave][k4 * 4];
      chv += c4[0] * bf2f(wr[(size_t)(k4 * 4 + 0) * 512])
           + c4[1] * bf2f(wr[(size_t)(k4 * 4 + 1) * 512])
           + c4[2] * bf2f(wr[(size_t)(k4 * 4 + 2) * 512])
           + c4[3] * bf2f(wr[(size_t)(k4 * 4 + 3) * 512]);
    }
  }
  ch[tid] = chv;
  __syncthreads();

  float o = 0.f;
#pragma unroll 8
  for (int d = 0; d < 64; d++)
    o += ch[wave * 64 + d] * ldf(wv, ((size_t)(wave * 64 + d) << 6) + lane, dt);
  size_t oi = (size_t)(bg * 8 + wave) * 64 + lane;
  stf(out, oi, dt, o + ldf(q, oi, dt));
}

extern "C" void kernel_launch(void* const* d_in, const int* in_sizes, int n_in,
                              void* d_out, int out_size, void* d_ws, size_t ws_size,
                              hipStream_t stream) {
  (void)in_sizes; (void)n_in; (void)out_size;
  const void* q   = d_in[0];
  const void* seq = d_in[1];
  const void* rw  = d_in[2];
  const void* w1  = d_in[3];
  const void* w2  = d_in[4];
  const void* w3  = d_in[5];
  const void* wk  = d_in[6];
  const void* wv  = d_in[7];
  const int*  msk = (const int*)d_in[8];

  char* ws = (char*)d_ws;
  size_t off = 0;
  auto alloc = [&](size_t b) { void* p = ws + off; off = (off + b + 255) & ~(size_t)255; return p; };
  int*   flags = (int*)alloc(512);            // [0]=mflag, [4]=dflag
  int*   mflag = flags + 0;
  int*   dflag = flags + 4;
  u16t*  Xn    = (u16t*)alloc((size_t)BT_ROWS * MODEL * 2);
  u16t*  W1t   = (u16t*)alloc((size_t)FFNH * MODEL * 2);
  u16t*  W2t   = (u16t*)alloc((size_t)FFNH * MODEL * 2);
  u16t*  W3bf  = (u16t*)alloc((size_t)FFNH * MODEL * 2);
  float* qkg   = (float*)alloc((size_t)256 * 8 * 64 * 4);
  float* w3qk  = (float*)alloc((size_t)8 * 256 * FFNH * 4);
  float* scb   = (float*)alloc((size_t)256 * 8 * 200 * 4);
  float* ctxaG = (float*)alloc((size_t)2 * 128 * 8 * FFNH * 4);
  float* ctxsG = (float*)alloc((size_t)2 * 128 * 512 * 4);
  size_t actBytes = (ws_size > off) ? (ws_size - off) : 0;
  size_t unitB = (size_t)25 * 128 * FFNH * 2;       // 25 tiles = 16 batches = 13.1 MB
  long units = (long)(actBytes / unitB);
  if (units < 1) units = 1;
  if (units > 8) units = 8;
  int tpc = (int)units * 25;
  u16t* ActB = (u16t*)(ws + off);

  hipMemsetAsync(flags, 0, 512, stream);
  detect_dtype_k<<<dim3(1), dim3(256), 0, stream>>>((const unsigned int*)w1, dflag);
  detect_mask_k<<<dim3(50), dim3(256), 0, stream>>>((const unsigned int*)msk, mflag);

  rmsnorm_k<<<dim3(BT_ROWS / 4), dim3(256), 0, stream>>>(seq, rw, dflag, Xn);
  transpose_k<<<dim3(FFNH / 32, MODEL / 32), dim3(256), 0, stream>>>(w1, W1t, dflag, MODEL, FFNH);
  transpose_k<<<dim3(FFNH / 32, MODEL / 32), dim3(256), 0, stream>>>(w2, W2t, dflag, MODEL, FFNH);
  cast_w3_k<<<dim3(4096), dim3(256), 0, stream>>>(w3, dflag, W3bf);
  qk_k<<<dim3(2048), dim3(64), 0, stream>>>(q, wk, dflag, qkg);
  w3qk_k<<<dim3(8, 16), dim3(256), 0, stream>>>(w3, qkg, dflag, w3qk);

  for (int t0 = 0; t0 < 400; t0 += tpc) {
    int tiles = (400 - t0 < tpc) ? (400 - t0) : tpc;
    int rows0 = t0 * 128;
    int b0 = rows0 / 200;            // tiles multiple of 25 -> whole batches per chunk
    int bc = tiles * 128 / 200;
    ffn_gemm1<<<dim3(FFNH / 64, tiles), dim3(256), 0, stream>>>(
        Xn + (size_t)rows0 * MODEL, W1t, W2t, ActB);
    scores_k<<<dim3(bc, 2), dim3(512), 0, stream>>>(ActB, seq, qkg, w3qk, msk, mflag, dflag, scb, b0);
    pctx_k<<<dim3(bc, 2), dim3(512), 0, stream>>>(ActB, seq, scb, dflag, b0, ctxaG, ctxsG);
    chout_k<<<dim3(bc), dim3(512), 0, stream>>>(ctxaG, ctxsG, W3bf, wv, q, dflag, b0, d_out);
  }
}

// Round 9
// 1037.787 us; speedup vs baseline: 1.2945x; 1.0578x over previous
//
#include <hip/hip_runtime.h>
#include <hip/hip_fp16.h>
#include <cstdint>
#include <cstddef>

typedef unsigned short u16t;
typedef __bf16 bf16x8 __attribute__((ext_vector_type(8)));
typedef float f32x4 __attribute__((ext_vector_type(4)));
typedef unsigned short u16x8 __attribute__((ext_vector_type(8)));

#define BT_ROWS 51200   // B*T
#define MODEL 512
#define FFNH 2048

__device__ __forceinline__ float bf2f(u16t u) {
  union { unsigned int i; float f; } v; v.i = ((unsigned int)u) << 16; return v.f;
}
__device__ __forceinline__ u16t f2bf(float f) {
  union { float f; unsigned int i; } v; v.f = f;
  return (u16t)((v.i + 0x7fffu + ((v.i >> 16) & 1u)) >> 16);
}
// dt: 0 = bf16, 1 = fp32, 2 = fp16
__device__ __forceinline__ float ldf(const void* p, size_t i, int dt) {
  if (dt == 1) return ((const float*)p)[i];
  u16t u = ((const u16t*)p)[i];
  if (dt == 0) return bf2f(u);
  __half h; *(u16t*)&h = u; return __half2float(h);
}
__device__ __forceinline__ void stf(void* p, size_t i, int dt, float f) {
  if (dt == 1) { ((float*)p)[i] = f; }
  else if (dt == 0) { ((u16t*)p)[i] = f2bf(f); }
  else { __half h = __float2half(f); ((u16t*)p)[i] = *(u16t*)&h; }
}
__device__ __forceinline__ void gl2lds16(const void* g, void* l) {
  __builtin_amdgcn_global_load_lds((const __attribute__((address_space(1))) void*)g,
                                   (__attribute__((address_space(3))) void*)l, 16, 0, 0);
}

// ---------------- dtype probe on w1: ONE block ----------------
__global__ __launch_bounds__(256) void detect_dtype_k(const unsigned int* __restrict__ w1,
                                                      int* __restrict__ dflag) {
  __shared__ int sh[8];
  unsigned int wb[8];
#pragma unroll
  for (int it = 0; it < 8; it++) wb[it] = w1[it * 256 + threadIdx.x];  // 8 KB, in-bounds all dtypes
  int a = 0, bc = 0;
#pragma unroll
  for (int it = 0; it < 8; it++) {
    unsigned int w = wb[it];
    u16t lo = (u16t)(w & 0xffffu), hi = (u16t)(w >> 16);
    float flo = bf2f(lo);
    a += (!(fabsf(flo) < 0.25f)) ? 1 : 0;             // fires only for fp32 mantissa noise
    __half hh; *(u16t*)&hh = hi; float fhi = __half2float(hh);
    bc += (fabsf(fhi) > 0.25f && fabsf(fhi) < 256.f) ? 1 : 0;  // fires for bf16 bit patterns
  }
#pragma unroll
  for (int o = 32; o; o >>= 1) { a += __shfl_xor(a, o); bc += __shfl_xor(bc, o); }
  int w = threadIdx.x >> 6;
  if ((threadIdx.x & 63) == 0) { sh[w] = a; sh[4 + w] = bc; }
  __syncthreads();
  if (threadIdx.x == 0) {
    int A = sh[0] + sh[1] + sh[2] + sh[3];
    int B = sh[4] + sh[5] + sh[6] + sh[7];
    dflag[0] = (A > 128) ? 1 : ((B < 128) ? 2 : 0);   // 1=fp32, 2=fp16, 0=bf16
  }
}

// ---------------- Mask layout probe: flag=1 if byte-packed ----------------
__global__ __launch_bounds__(256) void detect_mask_k(const unsigned int* __restrict__ msk,
                                                     int* __restrict__ flag) {
  int i = blockIdx.x * 256 + threadIdx.x;
  int bad = 0;
  if (i < 12800) bad = (msk[i] > 1u) ? 1 : 0;        // exactly 51200 bytes, safe for int8 & int32
  unsigned long long bl = __ballot(bad);
  if ((threadIdx.x & 63) == 0 && bl) atomicOr(flag, 1);
}

// ---------------- RMSNorm: one wave per row of 512, output bf16 ----------------
__global__ __launch_bounds__(256) void rmsnorm_k(const void* __restrict__ seq,
                                                 const void* __restrict__ w,
                                                 const int* __restrict__ dfp,
                                                 u16t* __restrict__ xn) {
  const int dt = dfp[0];
  int row = blockIdx.x * 4 + (threadIdx.x >> 6);
  int lane = threadIdx.x & 63;
  size_t base = (size_t)row * MODEL + lane * 8;
  float x[8]; float ss = 0.f;
  if (dt == 0) {
    u16x8 xv = *(const u16x8*)((const u16t*)seq + base);
#pragma unroll
    for (int j = 0; j < 8; j++) { x[j] = bf2f(xv[j]); ss += x[j] * x[j]; }
  } else if (dt == 1) {
    const f32x4* p = (const f32x4*)((const float*)seq + base);
    f32x4 va = p[0], vb = p[1];
#pragma unroll
    for (int j = 0; j < 4; j++) { x[j] = va[j]; x[4 + j] = vb[j]; }
#pragma unroll
    for (int j = 0; j < 8; j++) ss += x[j] * x[j];
  } else {
#pragma unroll
    for (int j = 0; j < 8; j++) { x[j] = ldf(seq, base + j, dt); ss += x[j] * x[j]; }
  }
#pragma unroll
  for (int o = 32; o; o >>= 1) ss += __shfl_xor(ss, o);
  float rstd = rsqrtf(ss * (1.f / 512.f) + 1.1920929e-07f);
  u16x8 ov;
#pragma unroll
  for (int j = 0; j < 8; j++) ov[j] = f2bf(x[j] * rstd * ldf(w, lane * 8 + j, dt));
  *(u16x8*)(xn + base) = ov;
}

// ---------------- Transpose (R x C) -> (C x R) with dtype conversion to bf16 ----------------
__global__ __launch_bounds__(256) void transpose_k(const void* __restrict__ src,
                                                   u16t* __restrict__ dst,
                                                   const int* __restrict__ dfp,
                                                   int R, int C) {
  const int dt = dfp[0];
  __shared__ u16t tile[32][33];
  int x = threadIdx.x & 31, y = threadIdx.x >> 5;
  int c0 = blockIdx.x * 32, r0 = blockIdx.y * 32;
#pragma unroll
  for (int i = 0; i < 32; i += 8)
    tile[y + i][x] = f2bf(ldf(src, (size_t)(r0 + y + i) * C + c0 + x, dt));
  __syncthreads();
#pragma unroll
  for (int i = 0; i < 32; i += 8) dst[(size_t)(c0 + y + i) * R + r0 + x] = tile[x][y + i];
}

// LDS K-group XOR swizzle: physical group = logical ^ (row & 7). 2-way banks (free).
// Staging permutes the SOURCE k-group so data lands swizzled.

// ---------------- GEMM1: Act = silu(Xn@w1) * (Xn@w2), BM=128 BN=64 BK=64 ----------------
__global__ __launch_bounds__(256, 4) void ffn_gemm1(const u16t* __restrict__ Xn,
                                                    const u16t* __restrict__ W1t,
                                                    const u16t* __restrict__ W2t,
                                                    u16t* __restrict__ Act) {
  __shared__ u16t As[128 * 64];
  __shared__ u16t B1s[64 * 64];
  __shared__ u16t B2s[64 * 64];
  const int tid = threadIdx.x;
  const int lane = tid & 63;
  const int wave = tid >> 6;
  const int wr = wave >> 1, wc = wave & 1;
  const int quad = lane >> 4, l16 = lane & 15;
  const int nBase = blockIdx.x * 64;
  const int mBase = blockIdx.y * 128;
  const int wuBase = tid & ~63;

  f32x4 acc1[4][2], acc2[4][2];
  const f32x4 zf = {0.f, 0.f, 0.f, 0.f};
#pragma unroll
  for (int i = 0; i < 4; i++)
#pragma unroll
    for (int j = 0; j < 2; j++) { acc1[i][j] = zf; acc2[i][j] = zf; }

  for (int kt = 0; kt < MODEL; kt += 64) {
#pragma unroll
    for (int c = 0; c < 4; c++) {
      int chunk = c * 256 + tid;
      int r = chunk >> 3, k8 = (chunk & 7) ^ (r & 7);
      gl2lds16(Xn + (size_t)(mBase + r) * MODEL + kt + k8 * 8, As + (size_t)(c * 256 + wuBase) * 8);
    }
#pragma unroll
    for (int c = 0; c < 2; c++) {
      int chunk = c * 256 + tid;
      int r = chunk >> 3, k8 = (chunk & 7) ^ (r & 7);
      gl2lds16(W1t + (size_t)(nBase + r) * MODEL + kt + k8 * 8, B1s + (size_t)(c * 256 + wuBase) * 8);
      gl2lds16(W2t + (size_t)(nBase + r) * MODEL + kt + k8 * 8, B2s + (size_t)(c * 256 + wuBase) * 8);
    }
    __syncthreads();
#pragma unroll
    for (int ks = 0; ks < 64; ks += 32) {
      bf16x8 a[4], b1[2], b2[2];
      const int sw = (ks >> 3) + quad;
#pragma unroll
      for (int mi = 0; mi < 4; mi++) {
        int row = wr * 64 + mi * 16 + l16;
        a[mi] = *(const bf16x8*)(As + row * 64 + ((sw ^ (row & 7)) << 3));
      }
#pragma unroll
      for (int ni = 0; ni < 2; ni++) {
        int row = wc * 32 + ni * 16 + l16;
        b1[ni] = *(const bf16x8*)(B1s + row * 64 + ((sw ^ (row & 7)) << 3));
        b2[ni] = *(const bf16x8*)(B2s + row * 64 + ((sw ^ (row & 7)) << 3));
      }
#pragma unroll
      for (int mi = 0; mi < 4; mi++)
#pragma unroll
        for (int ni = 0; ni < 2; ni++) {
          acc1[mi][ni] = __builtin_amdgcn_mfma_f32_16x16x32_bf16(a[mi], b1[ni], acc1[mi][ni], 0, 0, 0);
          acc2[mi][ni] = __builtin_amdgcn_mfma_f32_16x16x32_bf16(a[mi], b2[ni], acc2[mi][ni], 0, 0, 0);
        }
    }
    __syncthreads();
  }
#pragma unroll
  for (int mi = 0; mi < 4; mi++)
#pragma unroll
    for (int ni = 0; ni < 2; ni++)
#pragma unroll
      for (int r = 0; r < 4; r++) {
        int row = mBase + wr * 64 + mi * 16 + quad * 4 + r;
        int col = nBase + wc * 32 + ni * 16 + l16;
        float g1 = acc1[mi][ni][r], g2 = acc2[mi][ni][r];
        float sl = g1 / (1.f + __expf(-g1));
        Act[(size_t)row * FFNH + col] = f2bf(sl * g2);
      }
}

// ---------------- GEMM2: H = Act@w3 + seq, BM=256 BN=128 BK=64, 512 threads ----------------
// 8 waves -> 256 MFMA per barrier (2x round-6); LDS 48 KB -> 3 blocks/CU.
__global__ __launch_bounds__(512, 6) void ffn_gemm2(const u16t* __restrict__ Act,
                                                    const u16t* __restrict__ W3t,
                                                    const void* __restrict__ Seq,
                                                    const int* __restrict__ dfp,
                                                    u16t* __restrict__ H, int rowOff) {
  __shared__ u16t As[256 * 64];   // 32 KB
  __shared__ u16t Bs[128 * 64];   // 16 KB
  const int dt = dfp[0];
  const int tid = threadIdx.x;
  const int lane = tid & 63;
  const int wave = tid >> 6;          // 0..7
  const int wr = wave >> 1, wc = wave & 1;
  const int quad = lane >> 4, l16 = lane & 15;
  const int nBase = blockIdx.x * 128;
  const int mBase = blockIdx.y * 256;
  const int wuBase = tid & ~63;

  f32x4 acc[4][4];
  const f32x4 zf = {0.f, 0.f, 0.f, 0.f};
#pragma unroll
  for (int i = 0; i < 4; i++)
#pragma unroll
    for (int j = 0; j < 4; j++) acc[i][j] = zf;

  for (int kt = 0; kt < FFNH; kt += 64) {
#pragma unroll
    for (int c = 0; c < 4; c++) {     // A: 256*64/8 = 2048 chunks / 512 thr
      int chunk = c * 512 + tid;
      int r = chunk >> 3, k8 = (chunk & 7) ^ (r & 7);
      gl2lds16(Act + (size_t)(mBase + r) * FFNH + kt + k8 * 8, As + (size_t)(c * 512 + wuBase) * 8);
    }
#pragma unroll
    for (int c = 0; c < 2; c++) {     // B: 128*64/8 = 1024 chunks
      int chunk = c * 512 + tid;
      int r = chunk >> 3, k8 = (chunk & 7) ^ (r & 7);
      gl2lds16(W3t + (size_t)(nBase + r) * FFNH + kt + k8 * 8, Bs + (size_t)(c * 512 + wuBase) * 8);
    }
    __syncthreads();
#pragma unroll
    for (int ks = 0; ks < 64; ks += 32) {
      bf16x8 a[4], b[4];
      const int sw = (ks >> 3) + quad;
#pragma unroll
      for (int mi = 0; mi < 4; mi++) {
        int row = wr * 64 + mi * 16 + l16;          // 0..255
        a[mi] = *(const bf16x8*)(As + row * 64 + ((sw ^ (row & 7)) << 3));
      }
#pragma unroll
      for (int ni = 0; ni < 4; ni++) {
        int row = wc * 64 + ni * 16 + l16;          // 0..127
        b[ni] = *(const bf16x8*)(Bs + row * 64 + ((sw ^ (row & 7)) << 3));
      }
#pragma unroll
      for (int mi = 0; mi < 4; mi++)
#pragma unroll
        for (int ni = 0; ni < 4; ni++)
          acc[mi][ni] = __builtin_amdgcn_mfma_f32_16x16x32_bf16(a[mi], b[ni], acc[mi][ni], 0, 0, 0);
    }
    __syncthreads();
  }
#pragma unroll
  for (int mi = 0; mi < 4; mi++)
#pragma unroll
    for (int ni = 0; ni < 4; ni++)
#pragma unroll
      for (int r = 0; r < 4; r++) {
        int grow = rowOff + mBase + wr * 64 + mi * 16 + quad * 4 + r;
        int col = nBase + wc * 64 + ni * 16 + l16;
        float v = acc[mi][ni][r] + ldf(Seq, (size_t)grow * MODEL + col, dt);
        H[(size_t)grow * MODEL + col] = f2bf(v);
      }
}

// ---------------- Attention: one block per (b, head), data-parallel phases ----------------
// LDS row stride 66 u16 -> bank = (t + d/2) % 32 : 2-way in both read phases (free).
__global__ __launch_bounds__(256) void attn_k(const u16t* __restrict__ H,
                                              const void* __restrict__ q,
                                              const void* __restrict__ wk,
                                              const void* __restrict__ wv,
                                              const int* __restrict__ mask,
                                              const int* __restrict__ mflagp,
                                              const int* __restrict__ dfp,
                                              void* __restrict__ out) {
  const int b = blockIdx.x >> 3;
  const int n = blockIdx.x & 7;
  const int tid = threadIdx.x;
  const int w = tid >> 6;
  const int lane = tid & 63;
  const int T = 200;
  const int HS = 66;
  const int dt = dfp[0];
  const int mflag = mflagp[0];

  __shared__ u16t hbuf[200 * HS];   // 26.4 KB
  __shared__ float qk[64];
  __shared__ float sc[200];
  __shared__ float part[256];
  __shared__ float red[8];
  __shared__ float ctx[64];

  for (int chunk = tid; chunk < 1600; chunk += 256) {
    int r = chunk >> 3, c = (chunk & 7) << 3;
    u16x8 v = *(const u16x8*)(H + (size_t)(b * 200 + r) * MODEL + n * 64 + c);
#pragma unroll
    for (int j = 0; j < 8; j++) hbuf[r * HS + c + j] = v[j];
  }

  {
    int d = tid >> 2, sub = tid & 3;
    float s = 0.f;
    size_t wb = ((size_t)(n * 64 + d) << 6) + sub * 16;
    size_t qb = ((size_t)(b * 8 + n) << 6) + sub * 16;
#pragma unroll
    for (int i = 0; i < 16; i++) s += ldf(wk, wb + i, dt) * ldf(q, qb + i, dt);
    part[tid] = s;
  }
  __syncthreads();
  if (tid < 64) qk[tid] = part[tid * 4] + part[tid * 4 + 1] + part[tid * 4 + 2] + part[tid * 4 + 3];
  __syncthreads();

  float sv = -INFINITY;
  if (tid < T) {
    float s = 0.f;
#pragma unroll 16
    for (int d = 0; d < 64; d++) s += bf2f(hbuf[tid * HS + d]) * qk[d];
    int mv = mflag ? (int)((const unsigned char*)mask)[b * 200 + tid] : mask[b * 200 + tid];
    sv = mv ? s * 0.125f : -INFINITY;
  }

  float mx = sv;
#pragma unroll
  for (int o = 32; o; o >>= 1) mx = fmaxf(mx, __shfl_xor(mx, o));
  if (lane == 0) red[w] = mx;
  __syncthreads();
  float gmax = fmaxf(fmaxf(red[0], red[1]), fmaxf(red[2], red[3]));
  float e = 0.f;
  if (gmax == -INFINITY) {
    if (tid == 0) e = 1.f;              // NaN guard (reference guarantees mask[:,0]=True)
  } else if (tid < T) {
    e = __expf(sv - gmax);
  }
  float s = e;
#pragma unroll
  for (int o = 32; o; o >>= 1) s += __shfl_xor(s, o);
  if (lane == 0) red[4 + w] = s;
  __syncthreads();
  float inv = 1.f / (red[4] + red[5] + red[6] + red[7]);
  if (tid < T) sc[tid] = e * inv;
  __syncthreads();

  float a2 = 0.f;
  for (int t = w; t < T; t += 4) a2 += sc[t] * bf2f(hbuf[t * HS + lane]);
  part[tid] = a2;
  __syncthreads();
  if (tid < 64) ctx[tid] = part[tid] + part[64 + tid] + part[128 + tid] + part[192 + tid];
  __syncthreads();

  {
    int od = tid & 63;
    float s2 = 0.f;
#pragma unroll
    for (int i = 0; i < 16; i++) {
      int d = w * 16 + i;
      s2 += ctx[d] * ldf(wv, ((size_t)(n * 64 + d) << 6) + od, dt);
    }
    part[tid] = s2;
  }
  __syncthreads();
  if (tid < 64) {
    size_t oi = (size_t)(b * 8 + tid / 64 * 0 + n) * 64 + tid;   // (b*8+n)*64 + tid
    oi = ((size_t)(b * 8 + n) << 6) + tid;
    stf(out, oi, dt,
        part[tid] + part[64 + tid] + part[128 + tid] + part[192 + tid] + ldf(q, oi, dt));
  }
}

extern "C" void kernel_launch(void* const* d_in, const int* in_sizes, int n_in,
                              void* d_out, int out_size, void* d_ws, size_t ws_size,
                              hipStream_t stream) {
  (void)in_sizes; (void)n_in; (void)out_size;
  const void* q   = d_in[0];
  const void* seq = d_in[1];
  const void* rw  = d_in[2];
  const void* w1  = d_in[3];
  const void* w2  = d_in[4];
  const void* w3  = d_in[5];
  const void* wk  = d_in[6];
  const void* wv  = d_in[7];
  const int*  msk = (const int*)d_in[8];

  char* ws = (char*)d_ws;
  size_t off = 0;
  auto alloc = [&](size_t b) { void* p = ws + off; off = (off + b + 255) & ~(size_t)255; return p; };
  int*  flags = (int*)alloc(512);            // [0]=mflag, [4]=dflag
  int*  mflag = flags + 0;
  int*  dflag = flags + 4;
  u16t* Xn  = (u16t*)alloc((size_t)BT_ROWS * MODEL * 2);   // reused as H in-place per chunk
  u16t* W1t = (u16t*)alloc((size_t)FFNH * MODEL * 2);
  u16t* W2t = (u16t*)alloc((size_t)FFNH * MODEL * 2);
  u16t* W3t = (u16t*)alloc((size_t)MODEL * FFNH * 2);
  size_t actBytes = (ws_size > off) ? (ws_size - off) : 0;
  long tpc = (long)(actBytes / ((size_t)128 * FFNH * 2));
  tpc &= ~1L;                 // even: gemm2 BM=256 needs 256-row granularity
  if (tpc < 2) tpc = 2;
  if (tpc > 200) tpc = 200;   // 200 tiles -> 105 MB Act chunk, L3-resident gemm1->gemm2
  u16t* ActB = (u16t*)(ws + off);

  hipMemsetAsync(flags, 0, 512, stream);
  detect_dtype_k<<<dim3(1), dim3(256), 0, stream>>>((const unsigned int*)w1, dflag);
  detect_mask_k<<<dim3(50), dim3(256), 0, stream>>>((const unsigned int*)msk, mflag);

  rmsnorm_k<<<dim3(BT_ROWS / 4), dim3(256), 0, stream>>>(seq, rw, dflag, Xn);
  transpose_k<<<dim3(FFNH / 32, MODEL / 32), dim3(256), 0, stream>>>(w1, W1t, dflag, MODEL, FFNH);
  transpose_k<<<dim3(FFNH / 32, MODEL / 32), dim3(256), 0, stream>>>(w2, W2t, dflag, MODEL, FFNH);
  transpose_k<<<dim3(MODEL / 32, FFNH / 32), dim3(256), 0, stream>>>(w3, W3t, dflag, FFNH, MODEL);

  for (int t0 = 0; t0 < 400; t0 += (int)tpc) {
    int tiles = (400 - t0 < (int)tpc) ? (400 - t0) : (int)tpc;
    int rows0 = t0 * 128;
    ffn_gemm1<<<dim3(FFNH / 64, tiles), dim3(256), 0, stream>>>(
        Xn + (size_t)rows0 * MODEL, W1t, W2t, ActB);
    ffn_gemm2<<<dim3(MODEL / 128, tiles / 2), dim3(512), 0, stream>>>(
        ActB, W3t, seq, dflag, Xn, rows0);
  }
  attn_k<<<dim3(2048), dim3(256), 0, stream>>>(Xn, q, wk, wv, msk, mflag, dflag, d_out);
}